// Round 5
// baseline (447.280 us; speedup 1.0000x reference)
//
#include <hip/hip_runtime.h>
#include <cstdint>
#include <cstddef>

#define H_DIM 1024
#define HEADS 16
#define HD 64
#define BATCH 4
#define SEQ 2048
#define M_ROWS (BATCH*SEQ)   // 8192

typedef __bf16 bf16x8 __attribute__((ext_vector_type(8)));
typedef float floatx4 __attribute__((ext_vector_type(4)));
typedef unsigned short ushortx8 __attribute__((ext_vector_type(8)));

__device__ __forceinline__ unsigned short f2bf(float f) {
    union { float f; uint32_t u; } c; c.f = f;
    uint32_t u = c.u;
    u += 0x7fffu + ((u >> 16) & 1u);     // RNE
    return (unsigned short)(u >> 16);
}
__device__ __forceinline__ float bf2f(unsigned short h) {
    union { uint32_t u; float f; } c; c.u = ((uint32_t)h) << 16;
    return c.f;
}

// async global->LDS, 16B per lane; LDS dest = wave-uniform base + lane*16 (m104/m108)
#define GLD_LDS16(gp, lp) \
    __builtin_amdgcn_global_load_lds((__attribute__((address_space(1))) void*)(gp), \
                                     (__attribute__((address_space(3))) void*)(lp), 16, 0, 0)

// ---------------- elementwise f32 -> bf16 cast (8 elems/thread) ----------------
__global__ __launch_bounds__(256) void cast_bf16(const float* __restrict__ in,
                                                 unsigned short* __restrict__ out)
{
    size_t i = (size_t)blockIdx.x * 256 + threadIdx.x;
    const float4* p = (const float4*)in;
    float4 a = p[i * 2], b = p[i * 2 + 1];
    ushortx8 o;
    o[0] = f2bf(a.x); o[1] = f2bf(a.y); o[2] = f2bf(a.z); o[3] = f2bf(a.w);
    o[4] = f2bf(b.x); o[5] = f2bf(b.y); o[6] = f2bf(b.z); o[7] = f2bf(b.w);
    *(ushortx8*)(out + i * 8) = o;
}

// ---------------- bf16 MFMA GEMM: C[m,n] = sum_k A[m,k]*W[n,k] + bias[n] ------
enum { EPI_NONE = 0, EPI_PHI = 1 };

__device__ __forceinline__ void store_out(float* C, size_t idx, float x) { C[idx] = x; }
__device__ __forceinline__ void store_out(unsigned short* C, size_t idx, float x) { C[idx] = f2bf(x); }

template<int EPI, typename OutT>
__global__ __launch_bounds__(256) void gemm_mfma(const unsigned short* __restrict__ A,  // [M,K] bf16
                                                 const unsigned short* __restrict__ W,  // [N,K] bf16
                                                 const float* __restrict__ bias,
                                                 OutT* __restrict__ C,
                                                 int M, int N, int K)
{
    constexpr int TM = 128, TN = 128, TK = 32;
    __shared__ __align__(16) unsigned short Ast[TM * TK];
    __shared__ __align__(16) unsigned short Bst[TN * TK];

    const int tid  = threadIdx.x;
    const int wave = tid >> 6;
    const int lane = tid & 63;
    const int bm = blockIdx.y * TM;
    const int bn = blockIdx.x * TN;

    const int srow  = wave * 16 + (lane >> 2);
    const int skoff = (lane & 3) * 8;

    const int wm   = (wave & 1) * 64;
    const int wn   = (wave >> 1) * 64;
    const int quad = lane >> 4;
    const int l16  = lane & 15;

    floatx4 acc[4][4] = {};

    const unsigned short* Abase = A + (size_t)bm * K;
    const unsigned short* Wbase = W + (size_t)bn * K;

    for (int k0 = 0; k0 < K; k0 += TK) {
        __syncthreads();
        GLD_LDS16(Abase + (size_t)srow        * K + k0 + skoff, &Ast[(wave * 16)      * TK]);
        GLD_LDS16(Abase + (size_t)(srow + 64) * K + k0 + skoff, &Ast[(64 + wave * 16) * TK]);
        GLD_LDS16(Wbase + (size_t)srow        * K + k0 + skoff, &Bst[(wave * 16)      * TK]);
        GLD_LDS16(Wbase + (size_t)(srow + 64) * K + k0 + skoff, &Bst[(64 + wave * 16) * TK]);
        __syncthreads();

        bf16x8 af[4], bfr[4];
        #pragma unroll
        for (int i = 0; i < 4; ++i)
            af[i] = *(const bf16x8*)&Ast[(wm + i * 16 + l16) * TK + quad * 8];
        #pragma unroll
        for (int j = 0; j < 4; ++j)
            bfr[j] = *(const bf16x8*)&Bst[(wn + j * 16 + l16) * TK + quad * 8];
        #pragma unroll
        for (int i = 0; i < 4; ++i)
            #pragma unroll
            for (int j = 0; j < 4; ++j)
                acc[i][j] = __builtin_amdgcn_mfma_f32_16x16x32_bf16(af[i], bfr[j], acc[i][j], 0, 0, 0);
    }

    #pragma unroll
    for (int i = 0; i < 4; ++i) {
        #pragma unroll
        for (int j = 0; j < 4; ++j) {
            const int col = bn + wn + j * 16 + l16;
            const float bval = bias[col];
            #pragma unroll
            for (int r = 0; r < 4; ++r) {
                const int row = bm + wm + i * 16 + quad * 4 + r;
                float x = acc[i][j][r] + bval;
                if (EPI == EPI_PHI) x = (x > 0.f) ? (x + 1.f) : __expf(x);  // elu(x)+1
                store_out(C, (size_t)row * N + col, x);
            }
        }
    }
}

// ---------------- b = sigmoid(beta @ Wb^T + bb) : [8192,16], fp32 -------------
// Wave-per-row: lane = (n in 0..15, kq in 0..3). Each lane dots 256 k-elems for
// one output n (no redundant FMAs), then xor-tree shuffle reduce over kq.
__global__ __launch_bounds__(256) void proj_b(const float* __restrict__ beta,
                                              const float* __restrict__ Wb,
                                              const float* __restrict__ bbias,
                                              float* __restrict__ bout)
{
    const int wave = threadIdx.x >> 6;
    const int lane = threadIdx.x & 63;
    const int m  = blockIdx.x * 4 + wave;
    const int n  = lane & 15;
    const int kq = lane >> 4;           // k-quarter: 256 elems = 64 float4s

    const float4* brow = (const float4*)(beta + (size_t)m * H_DIM) + kq * 64;
    const float4* wrow = (const float4*)(Wb   + (size_t)n * H_DIM) + kq * 64;

    float s = 0.f;
    #pragma unroll 8
    for (int j = 0; j < 64; ++j) {
        float4 a = brow[j], w = wrow[j];
        s = fmaf(a.x, w.x, s); s = fmaf(a.y, w.y, s);
        s = fmaf(a.z, w.z, s); s = fmaf(a.w, w.w, s);
    }
    s += __shfl_down(s, 32);
    s += __shfl_down(s, 16);
    if (lane < 16) {
        s += bbias[n];
        bout[(size_t)m * HEADS + n] = 1.f / (1.f + __expf(-s));
    }
}

// ---------------- chunked parallel linear scan -------------------------------
// s_t = a_t*s_{t-1} + c_t with a = 1 - b*pk^2, c = b*v*pk.
constexpr int NCHUNK = 64;
constexpr int CLEN   = SEQ / NCHUNK;     // 32
constexpr int NGH    = BATCH * HEADS * HD;  // 4096 independent lanes

__global__ __launch_bounds__(256) void scan_phase1(const unsigned short* __restrict__ pk_,
                                                   const unsigned short* __restrict__ v_,
                                                   const float* __restrict__ b_,
                                                   float* __restrict__ Aarr,
                                                   float* __restrict__ Carr)
{
    const int idx   = blockIdx.x * 256 + threadIdx.x;   // 0 .. NGH*NCHUNK-1
    const int d     = idx & 63;
    const int h     = (idx >> 6) & 15;
    const int bb    = (idx >> 10) & 3;
    const int chunk = idx >> 12;
    const int g     = idx & (NGH - 1);
    const int t0    = chunk * CLEN;

    const unsigned short* pkp = pk_ + (size_t)bb * SEQ * H_DIM + h * HD + d + (size_t)t0 * H_DIM;
    const unsigned short* vp  = v_  + (size_t)bb * SEQ * H_DIM + h * HD + d + (size_t)t0 * H_DIM;
    const float*          bp  = b_  + (size_t)bb * SEQ * HEADS + h        + (size_t)t0 * HEADS;

    float A = 1.f, C = 0.f;
    #pragma unroll 8
    for (int t = 0; t < CLEN; ++t) {
        float pk = bf2f(pkp[(size_t)t * H_DIM]);
        float vv = bf2f(vp[(size_t)t * H_DIM]);
        float bt = bp[(size_t)t * HEADS];
        float a  = 1.f - bt * pk * pk;
        float c  = bt * vv * pk;
        A *= a;
        C = fmaf(a, C, c);
    }
    Aarr[(size_t)chunk * NGH + g] = A;
    Carr[(size_t)chunk * NGH + g] = C;
}

__global__ __launch_bounds__(256) void scan_phase2(const float* __restrict__ Aarr,
                                                   const float* __restrict__ Carr,
                                                   float* __restrict__ S0)
{
    const int g = blockIdx.x * 256 + threadIdx.x;   // 0..4095
    float s = 0.f;
    #pragma unroll
    for (int c = 0; c < NCHUNK; ++c) {
        S0[(size_t)c * NGH + g] = s;
        s = fmaf(Aarr[(size_t)c * NGH + g], s, Carr[(size_t)c * NGH + g]);
    }
}

__global__ __launch_bounds__(256) void scan_phase3(const unsigned short* __restrict__ pk_,
                                                   unsigned short* __restrict__ pq_,   // in: phi_q, out: ys
                                                   const unsigned short* __restrict__ v_,
                                                   const float* __restrict__ b_,
                                                   const float* __restrict__ S0)
{
    const int idx   = blockIdx.x * 256 + threadIdx.x;
    const int d     = idx & 63;
    const int h     = (idx >> 6) & 15;
    const int bb    = (idx >> 10) & 3;
    const int chunk = idx >> 12;
    const int g     = idx & (NGH - 1);
    const int t0    = chunk * CLEN;

    const unsigned short* pkp = pk_ + (size_t)bb * SEQ * H_DIM + h * HD + d + (size_t)t0 * H_DIM;
    unsigned short*       pqp = pq_ + (size_t)bb * SEQ * H_DIM + h * HD + d + (size_t)t0 * H_DIM;
    const unsigned short* vp  = v_  + (size_t)bb * SEQ * H_DIM + h * HD + d + (size_t)t0 * H_DIM;
    const float*          bp  = b_  + (size_t)bb * SEQ * HEADS + h        + (size_t)t0 * HEADS;

    float s = S0[(size_t)chunk * NGH + g];
    #pragma unroll 8
    for (int t = 0; t < CLEN; ++t) {
        float pk = bf2f(pkp[(size_t)t * H_DIM]);
        float pq = bf2f(pqp[(size_t)t * H_DIM]);
        float vv = bf2f(vp[(size_t)t * H_DIM]);
        float bt = bp[(size_t)t * HEADS];
        float bdv = bt * (vv - s * pk);   // identical op order to the sequential version
        s = fmaf(bdv, pk, s);
        pqp[(size_t)t * H_DIM] = f2bf(s * pq);
    }
}

extern "C" void kernel_launch(void* const* d_in, const int* in_sizes, int n_in,
                              void* d_out, int out_size, void* d_ws, size_t ws_size,
                              hipStream_t stream)
{
    const float* query = (const float*)d_in[0];
    const float* key   = (const float*)d_in[1];
    const float* value = (const float*)d_in[2];
    const float* beta  = (const float*)d_in[3];
    const float* Wq    = (const float*)d_in[4];
    const float* bq    = (const float*)d_in[5];
    const float* Wk    = (const float*)d_in[6];
    const float* bk    = (const float*)d_in[7];
    const float* Wv    = (const float*)d_in[8];
    const float* bv    = (const float*)d_in[9];
    const float* Wb    = (const float*)d_in[10];
    const float* bbias = (const float*)d_in[11];
    const float* Wo    = (const float*)d_in[12];
    const float* bo    = (const float*)d_in[13];
    float* out = (float*)d_out;

    const size_t ACT = (size_t)M_ROWS * H_DIM;   // 8 Mi elems
    const size_t WEL = (size_t)H_DIM * H_DIM;    // 1 Mi elems

    unsigned short* ws = (unsigned short*)d_ws;
    unsigned short* Xbf    = ws;                 // staging for cast input (reused serially)
    unsigned short* phi_q  = ws + ACT;           // bf16 [8192,1024]; ys written in-place
    unsigned short* phi_k  = ws + 2 * ACT;
    unsigned short* vbuf   = ws + 3 * ACT;
    unsigned short* Wq_bf  = ws + 4 * ACT;
    unsigned short* Wk_bf  = Wq_bf + WEL;
    unsigned short* Wv_bf  = Wk_bf + WEL;
    unsigned short* Wo_bf  = Wv_bf + WEL;
    float*          bbuf   = (float*)(Wo_bf + WEL);        // [8192,16]
    float*          Aarr   = bbuf + (size_t)M_ROWS * HEADS; // [64][4096]
    float*          Carr   = Aarr + (size_t)NCHUNK * NGH;
    float*          S0     = Carr + (size_t)NCHUNK * NGH;

    const int ACT_CAST_BLOCKS = (int)(ACT / (8 * 256));   // 4096
    const int W_CAST_BLOCKS   = (int)(WEL / (8 * 256));   // 512

    cast_bf16<<<W_CAST_BLOCKS, 256, 0, stream>>>(Wq, Wq_bf);
    cast_bf16<<<W_CAST_BLOCKS, 256, 0, stream>>>(Wk, Wk_bf);
    cast_bf16<<<W_CAST_BLOCKS, 256, 0, stream>>>(Wv, Wv_bf);
    cast_bf16<<<W_CAST_BLOCKS, 256, 0, stream>>>(Wo, Wo_bf);

    dim3 ggrid(H_DIM / 128, M_ROWS / 128);   // (8, 64) = 512 blocks

    cast_bf16<<<ACT_CAST_BLOCKS, 256, 0, stream>>>(query, Xbf);
    gemm_mfma<EPI_PHI, unsigned short><<<ggrid, 256, 0, stream>>>(Xbf, Wq_bf, bq, phi_q, M_ROWS, H_DIM, H_DIM);
    cast_bf16<<<ACT_CAST_BLOCKS, 256, 0, stream>>>(key, Xbf);
    gemm_mfma<EPI_PHI, unsigned short><<<ggrid, 256, 0, stream>>>(Xbf, Wk_bf, bk, phi_k, M_ROWS, H_DIM, H_DIM);
    cast_bf16<<<ACT_CAST_BLOCKS, 256, 0, stream>>>(value, Xbf);
    gemm_mfma<EPI_NONE, unsigned short><<<ggrid, 256, 0, stream>>>(Xbf, Wv_bf, bv, vbuf, M_ROWS, H_DIM, H_DIM);

    proj_b<<<M_ROWS / 4, 256, 0, stream>>>(beta, Wb, bbias, bbuf);

    const int SCAN_BLOCKS = NGH * NCHUNK / 256;   // 1024
    scan_phase1<<<SCAN_BLOCKS, 256, 0, stream>>>(phi_k, vbuf, bbuf, Aarr, Carr);
    scan_phase2<<<NGH / 256, 256, 0, stream>>>(Aarr, Carr, S0);
    scan_phase3<<<SCAN_BLOCKS, 256, 0, stream>>>(phi_k, phi_q, vbuf, bbuf, S0);

    gemm_mfma<EPI_NONE, float><<<ggrid, 256, 0, stream>>>(phi_q, Wo_bf, bo, out, M_ROWS, H_DIM, H_DIM);
}

// Round 6
// 385.507 us; speedup vs baseline: 1.1602x; 1.1602x over previous
//
#include <hip/hip_runtime.h>
#include <cstdint>
#include <cstddef>

#define H_DIM 1024
#define HEADS 16
#define HD 64
#define BATCH 4
#define SEQ 2048
#define M_ROWS (BATCH*SEQ)   // 8192

typedef __bf16 bf16x8 __attribute__((ext_vector_type(8)));
typedef float floatx4 __attribute__((ext_vector_type(4)));
typedef unsigned short ushortx8 __attribute__((ext_vector_type(8)));

__device__ __forceinline__ unsigned short f2bf(float f) {
    union { float f; uint32_t u; } c; c.f = f;
    uint32_t u = c.u;
    u += 0x7fffu + ((u >> 16) & 1u);     // RNE
    return (unsigned short)(u >> 16);
}
__device__ __forceinline__ float bf2f(unsigned short h) {
    union { uint32_t u; float f; } c; c.u = ((uint32_t)h) << 16;
    return c.f;
}

// async global->LDS, 16B per lane; LDS dest = wave-uniform base + lane*16 (m104/m108)
#define GLD_LDS16(gp, lp) \
    __builtin_amdgcn_global_load_lds((__attribute__((address_space(1))) void*)(gp), \
                                     (__attribute__((address_space(3))) void*)(lp), 16, 0, 0)

// ---------------- elementwise f32 -> bf16 cast (8 elems/thread) ----------------
__global__ __launch_bounds__(256) void cast_bf16(const float* __restrict__ in,
                                                 unsigned short* __restrict__ out)
{
    size_t i = (size_t)blockIdx.x * 256 + threadIdx.x;
    const float4* p = (const float4*)in;
    float4 a = p[i * 2], b = p[i * 2 + 1];
    ushortx8 o;
    o[0] = f2bf(a.x); o[1] = f2bf(a.y); o[2] = f2bf(a.z); o[3] = f2bf(a.w);
    o[4] = f2bf(b.x); o[5] = f2bf(b.y); o[6] = f2bf(b.z); o[7] = f2bf(b.w);
    *(ushortx8*)(out + i * 8) = o;
}

// ---------------- bf16 MFMA GEMM: C[m,n] = sum_k A[m,k]*W[n,k] + bias[n] ------
enum { EPI_NONE = 0, EPI_PHI = 1 };

__device__ __forceinline__ void store_out(float* C, size_t idx, float x) { C[idx] = x; }
__device__ __forceinline__ void store_out(unsigned short* C, size_t idx, float x) { C[idx] = f2bf(x); }

template<int EPI, typename OutT>
__global__ __launch_bounds__(256) void gemm_mfma(const unsigned short* __restrict__ A,  // [M,K] bf16
                                                 const unsigned short* __restrict__ W,  // [N,K] bf16
                                                 const float* __restrict__ bias,
                                                 OutT* __restrict__ C,
                                                 int M, int N, int K)
{
    constexpr int TM = 128, TN = 128, TK = 32;
    __shared__ __align__(16) unsigned short Ast[TM * TK];
    __shared__ __align__(16) unsigned short Bst[TN * TK];

    const int tid  = threadIdx.x;
    const int wave = tid >> 6;
    const int lane = tid & 63;
    const int bm = blockIdx.y * TM;
    const int bn = blockIdx.x * TN;

    const int srow  = wave * 16 + (lane >> 2);
    const int skoff = (lane & 3) * 8;

    const int wm   = (wave & 1) * 64;
    const int wn   = (wave >> 1) * 64;
    const int quad = lane >> 4;
    const int l16  = lane & 15;

    floatx4 acc[4][4] = {};

    const unsigned short* Abase = A + (size_t)bm * K;
    const unsigned short* Wbase = W + (size_t)bn * K;

    for (int k0 = 0; k0 < K; k0 += TK) {
        __syncthreads();
        GLD_LDS16(Abase + (size_t)srow        * K + k0 + skoff, &Ast[(wave * 16)      * TK]);
        GLD_LDS16(Abase + (size_t)(srow + 64) * K + k0 + skoff, &Ast[(64 + wave * 16) * TK]);
        GLD_LDS16(Wbase + (size_t)srow        * K + k0 + skoff, &Bst[(wave * 16)      * TK]);
        GLD_LDS16(Wbase + (size_t)(srow + 64) * K + k0 + skoff, &Bst[(64 + wave * 16) * TK]);
        __syncthreads();

        bf16x8 af[4], bfr[4];
        #pragma unroll
        for (int i = 0; i < 4; ++i)
            af[i] = *(const bf16x8*)&Ast[(wm + i * 16 + l16) * TK + quad * 8];
        #pragma unroll
        for (int j = 0; j < 4; ++j)
            bfr[j] = *(const bf16x8*)&Bst[(wn + j * 16 + l16) * TK + quad * 8];
        #pragma unroll
        for (int i = 0; i < 4; ++i)
            #pragma unroll
            for (int j = 0; j < 4; ++j)
                acc[i][j] = __builtin_amdgcn_mfma_f32_16x16x32_bf16(af[i], bfr[j], acc[i][j], 0, 0, 0);
    }

    #pragma unroll
    for (int i = 0; i < 4; ++i) {
        #pragma unroll
        for (int j = 0; j < 4; ++j) {
            const int col = bn + wn + j * 16 + l16;
            const float bval = bias[col];
            #pragma unroll
            for (int r = 0; r < 4; ++r) {
                const int row = bm + wm + i * 16 + quad * 4 + r;
                float x = acc[i][j][r] + bval;
                if (EPI == EPI_PHI) x = (x > 0.f) ? (x + 1.f) : __expf(x);  // elu(x)+1
                store_out(C, (size_t)row * N + col, x);
            }
        }
    }
}

// ---------------- b = sigmoid(beta @ Wb^T + bb) : [8192,16], fp32 -------------
// v3: wave-per-row, FULLY COALESCED loads (lane l -> float4 element l). Each
// lane accumulates all 16 outputs; 6-stage shfl_xor butterfly per output.
// (v2 failed: (n,kq) lane split made every Wb load touch 64 cache lines.)
__global__ __launch_bounds__(256) void proj_b(const float* __restrict__ beta,
                                              const float* __restrict__ Wb,
                                              const float* __restrict__ bbias,
                                              float* __restrict__ bout)
{
    const int wave = threadIdx.x >> 6;
    const int lane = threadIdx.x & 63;
    const int m = blockIdx.x * 4 + wave;

    const float4* brow = (const float4*)(beta + (size_t)m * H_DIM);   // 256 float4
    const float4* wb4  = (const float4*)Wb;                            // [16][256] float4

    float acc[16];
    #pragma unroll
    for (int n = 0; n < 16; ++n) acc[n] = 0.f;

    #pragma unroll
    for (int j = 0; j < 4; ++j) {
        float4 a = brow[j * 64 + lane];            // 1KB coalesced
        #pragma unroll
        for (int n = 0; n < 16; ++n) {
            float4 w = wb4[n * 256 + j * 64 + lane];   // 1KB coalesced, L1/L2-hot
            acc[n] = fmaf(a.x, w.x, acc[n]);
            acc[n] = fmaf(a.y, w.y, acc[n]);
            acc[n] = fmaf(a.z, w.z, acc[n]);
            acc[n] = fmaf(a.w, w.w, acc[n]);
        }
    }

    #pragma unroll
    for (int n = 0; n < 16; ++n) {
        float s = acc[n];
        s += __shfl_xor(s, 32);
        s += __shfl_xor(s, 16);
        s += __shfl_xor(s, 8);
        s += __shfl_xor(s, 4);
        s += __shfl_xor(s, 2);
        s += __shfl_xor(s, 1);
        acc[n] = s;
    }

    // lane l (l<16) stores output n=l; select acc[l] without indexed-array spill
    float sel = acc[0];
    #pragma unroll
    for (int n = 1; n < 16; ++n)
        sel = (lane == n) ? acc[n] : sel;
    if (lane < 16) {
        float s = sel + bbias[lane];
        bout[(size_t)m * HEADS + lane] = 1.f / (1.f + __expf(-s));
    }
}

// ---------------- chunked parallel linear scan -------------------------------
// s_t = a_t*s_{t-1} + c_t with a = 1 - b*pk^2, c = b*v*pk.
constexpr int NCHUNK = 64;
constexpr int CLEN   = SEQ / NCHUNK;     // 32
constexpr int NGH    = BATCH * HEADS * HD;  // 4096 independent lanes

__global__ __launch_bounds__(256) void scan_phase1(const unsigned short* __restrict__ pk_,
                                                   const unsigned short* __restrict__ v_,
                                                   const float* __restrict__ b_,
                                                   float* __restrict__ Aarr,
                                                   float* __restrict__ Carr)
{
    const int idx   = blockIdx.x * 256 + threadIdx.x;   // 0 .. NGH*NCHUNK-1
    const int d     = idx & 63;
    const int h     = (idx >> 6) & 15;
    const int bb    = (idx >> 10) & 3;
    const int chunk = idx >> 12;
    const int g     = idx & (NGH - 1);
    const int t0    = chunk * CLEN;

    const unsigned short* pkp = pk_ + (size_t)bb * SEQ * H_DIM + h * HD + d + (size_t)t0 * H_DIM;
    const unsigned short* vp  = v_  + (size_t)bb * SEQ * H_DIM + h * HD + d + (size_t)t0 * H_DIM;
    const float*          bp  = b_  + (size_t)bb * SEQ * HEADS + h        + (size_t)t0 * HEADS;

    float A = 1.f, C = 0.f;
    #pragma unroll 8
    for (int t = 0; t < CLEN; ++t) {
        float pk = bf2f(pkp[(size_t)t * H_DIM]);
        float vv = bf2f(vp[(size_t)t * H_DIM]);
        float bt = bp[(size_t)t * HEADS];
        float a  = 1.f - bt * pk * pk;
        float c  = bt * vv * pk;
        A *= a;
        C = fmaf(a, C, c);
    }
    Aarr[(size_t)chunk * NGH + g] = A;
    Carr[(size_t)chunk * NGH + g] = C;
}

__global__ __launch_bounds__(256) void scan_phase2(const float* __restrict__ Aarr,
                                                   const float* __restrict__ Carr,
                                                   float* __restrict__ S0)
{
    const int g = blockIdx.x * 256 + threadIdx.x;   // 0..4095
    float s = 0.f;
    #pragma unroll
    for (int c = 0; c < NCHUNK; ++c) {
        S0[(size_t)c * NGH + g] = s;
        s = fmaf(Aarr[(size_t)c * NGH + g], s, Carr[(size_t)c * NGH + g]);
    }
}

__global__ __launch_bounds__(256) void scan_phase3(const unsigned short* __restrict__ pk_,
                                                   unsigned short* __restrict__ pq_,   // in: phi_q, out: ys
                                                   const unsigned short* __restrict__ v_,
                                                   const float* __restrict__ b_,
                                                   const float* __restrict__ S0)
{
    const int idx   = blockIdx.x * 256 + threadIdx.x;
    const int d     = idx & 63;
    const int h     = (idx >> 6) & 15;
    const int bb    = (idx >> 10) & 3;
    const int chunk = idx >> 12;
    const int g     = idx & (NGH - 1);
    const int t0    = chunk * CLEN;

    const unsigned short* pkp = pk_ + (size_t)bb * SEQ * H_DIM + h * HD + d + (size_t)t0 * H_DIM;
    unsigned short*       pqp = pq_ + (size_t)bb * SEQ * H_DIM + h * HD + d + (size_t)t0 * H_DIM;
    const unsigned short* vp  = v_  + (size_t)bb * SEQ * H_DIM + h * HD + d + (size_t)t0 * H_DIM;
    const float*          bp  = b_  + (size_t)bb * SEQ * HEADS + h        + (size_t)t0 * HEADS;

    float s = S0[(size_t)chunk * NGH + g];
    #pragma unroll 8
    for (int t = 0; t < CLEN; ++t) {
        float pk = bf2f(pkp[(size_t)t * H_DIM]);
        float pq = bf2f(pqp[(size_t)t * H_DIM]);
        float vv = bf2f(vp[(size_t)t * H_DIM]);
        float bt = bp[(size_t)t * HEADS];
        float bdv = bt * (vv - s * pk);   // identical op order to the sequential version
        s = fmaf(bdv, pk, s);
        pqp[(size_t)t * H_DIM] = f2bf(s * pq);
    }
}

extern "C" void kernel_launch(void* const* d_in, const int* in_sizes, int n_in,
                              void* d_out, int out_size, void* d_ws, size_t ws_size,
                              hipStream_t stream)
{
    const float* query = (const float*)d_in[0];
    const float* key   = (const float*)d_in[1];
    const float* value = (const float*)d_in[2];
    const float* beta  = (const float*)d_in[3];
    const float* Wq    = (const float*)d_in[4];
    const float* bq    = (const float*)d_in[5];
    const float* Wk    = (const float*)d_in[6];
    const float* bk    = (const float*)d_in[7];
    const float* Wv    = (const float*)d_in[8];
    const float* bv    = (const float*)d_in[9];
    const float* Wb    = (const float*)d_in[10];
    const float* bbias = (const float*)d_in[11];
    const float* Wo    = (const float*)d_in[12];
    const float* bo    = (const float*)d_in[13];
    float* out = (float*)d_out;

    const size_t ACT = (size_t)M_ROWS * H_DIM;   // 8 Mi elems
    const size_t WEL = (size_t)H_DIM * H_DIM;    // 1 Mi elems

    unsigned short* ws = (unsigned short*)d_ws;
    unsigned short* Xbf    = ws;                 // staging for cast input (reused serially)
    unsigned short* phi_q  = ws + ACT;           // bf16 [8192,1024]; ys written in-place
    unsigned short* phi_k  = ws + 2 * ACT;
    unsigned short* vbuf   = ws + 3 * ACT;
    unsigned short* Wq_bf  = ws + 4 * ACT;
    unsigned short* Wk_bf  = Wq_bf + WEL;
    unsigned short* Wv_bf  = Wk_bf + WEL;
    unsigned short* Wo_bf  = Wv_bf + WEL;
    float*          bbuf   = (float*)(Wo_bf + WEL);        // [8192,16]
    float*          Aarr   = bbuf + (size_t)M_ROWS * HEADS; // [64][4096]
    float*          Carr   = Aarr + (size_t)NCHUNK * NGH;
    float*          S0     = Carr + (size_t)NCHUNK * NGH;

    const int ACT_CAST_BLOCKS = (int)(ACT / (8 * 256));   // 4096
    const int W_CAST_BLOCKS   = (int)(WEL / (8 * 256));   // 512

    cast_bf16<<<W_CAST_BLOCKS, 256, 0, stream>>>(Wq, Wq_bf);
    cast_bf16<<<W_CAST_BLOCKS, 256, 0, stream>>>(Wk, Wk_bf);
    cast_bf16<<<W_CAST_BLOCKS, 256, 0, stream>>>(Wv, Wv_bf);
    cast_bf16<<<W_CAST_BLOCKS, 256, 0, stream>>>(Wo, Wo_bf);

    dim3 ggrid(H_DIM / 128, M_ROWS / 128);   // (8, 64) = 512 blocks

    cast_bf16<<<ACT_CAST_BLOCKS, 256, 0, stream>>>(query, Xbf);
    gemm_mfma<EPI_PHI, unsigned short><<<ggrid, 256, 0, stream>>>(Xbf, Wq_bf, bq, phi_q, M_ROWS, H_DIM, H_DIM);
    cast_bf16<<<ACT_CAST_BLOCKS, 256, 0, stream>>>(key, Xbf);
    gemm_mfma<EPI_PHI, unsigned short><<<ggrid, 256, 0, stream>>>(Xbf, Wk_bf, bk, phi_k, M_ROWS, H_DIM, H_DIM);
    cast_bf16<<<ACT_CAST_BLOCKS, 256, 0, stream>>>(value, Xbf);
    gemm_mfma<EPI_NONE, unsigned short><<<ggrid, 256, 0, stream>>>(Xbf, Wv_bf, bv, vbuf, M_ROWS, H_DIM, H_DIM);

    proj_b<<<M_ROWS / 4, 256, 0, stream>>>(beta, Wb, bbias, bbuf);

    const int SCAN_BLOCKS = NGH * NCHUNK / 256;   // 1024
    scan_phase1<<<SCAN_BLOCKS, 256, 0, stream>>>(phi_k, vbuf, bbuf, Aarr, Carr);
    scan_phase2<<<NGH / 256, 256, 0, stream>>>(Aarr, Carr, S0);
    scan_phase3<<<SCAN_BLOCKS, 256, 0, stream>>>(phi_k, phi_q, vbuf, bbuf, S0);

    gemm_mfma<EPI_NONE, float><<<ggrid, 256, 0, stream>>>(phi_q, Wo_bf, bo, out, M_ROWS, H_DIM, H_DIM);
}